// Round 11
// baseline (274.485 us; speedup 1.0000x reference)
//
#include <hip/hip_runtime.h>

// MultiHeadedAttention: B=1, S=4096, E=1024, H=16, D=64, fp32 in/out.
// R18: ATTRIBUTION ROUND. Mega-kernel arc abandoned (R16b race; R17
//   cooperative launch incompatible with hip-graph capture). Config
//   reverted to best-passing R13 (212.6us). k_gemm launched 3x
//   (idempotent, bit-identical output): dur_us - 212.6 = 2*t_gemm gives
//   the QKV-GEMM's true duration; if t_gemm > ~76us its dispatches enter
//   the top-5 WITH counters. Deliberate timing regression to buy the
//   number that R11-R14's neutral probes never produced.
// NOTE (R8):  cross-body software pipelining of attn spills to scratch.
// NOTE (R10): in-wave VALU/MFMA interleave pinning regresses.
// NOTE (R12/R14): GEMM latency pipelining / XCD swizzle / occupancy ~neutral.
// NOTE (R15): wave anti-phase neutral; attn MFMA pipe ~90% fed while active.
// NOTE (R16/R17): cross-kernel fusion requires grid sync; hand-rolled
//   barrier races (XCD L2 non-coherence), cooperative launch breaks
//   graph capture. Do not revisit without a verified in-graph barrier.

constexpr int Sq = 4096;
constexpr int Ee = 1024;
constexpr int Hh = 16;
constexpr int Dh = 64;

typedef _Float16 half8 __attribute__((ext_vector_type(8)));
typedef _Float16 half4 __attribute__((ext_vector_type(4)));
typedef _Float16 half2t __attribute__((ext_vector_type(2)));
typedef float f32x4 __attribute__((ext_vector_type(4)));

union U8 { half8 v8; half2t h2[4]; };

__device__ __forceinline__ unsigned short f2h(float f) {
  _Float16 h = (_Float16)f;
  return *reinterpret_cast<unsigned short*>(&h);
}

__device__ __forceinline__ half2t pk(float a, float b) {
  return __builtin_bit_cast(half2t, __builtin_amdgcn_cvt_pkrtz(a, b));
}

__device__ __forceinline__ void gload16(const void* g, void* l) {
  __builtin_amdgcn_global_load_lds(
      (const __attribute__((address_space(1))) void*)g,
      (__attribute__((address_space(3))) void*)l, 16, 0, 0);
}

// ---- fused prep: x fp32->f16 (blocks 0..4095) + 4 weight transposes ----
__global__ void k_prep(const float* __restrict__ x,
                       const float* __restrict__ Wq, const float* __restrict__ Wk,
                       const float* __restrict__ Wv, const float* __restrict__ Wo,
                       unsigned short* __restrict__ xb,
                       unsigned short* __restrict__ Wqt, unsigned short* __restrict__ Wkt,
                       unsigned short* __restrict__ Wvt, unsigned short* __restrict__ Wot) {
  int b = blockIdx.x, t = threadIdx.x;
  if (b < 4096) {
    int i = b * 256 + t;
    float4 v = reinterpret_cast<const float4*>(x)[i];
    ushort4 o;
    o.x = f2h(v.x); o.y = f2h(v.y); o.z = f2h(v.z); o.w = f2h(v.w);
    reinterpret_cast<ushort4*>(xb)[i] = o;
    return;
  }
  __shared__ unsigned short tile[64][65];
  int r = b - 4096;
  int wi = r >> 8, ti = r & 255;
  const float* W = (wi == 0) ? Wq : (wi == 1) ? Wk : (wi == 2) ? Wv : Wo;
  unsigned short* Wt = (wi == 0) ? Wqt : (wi == 1) ? Wkt : (wi == 2) ? Wvt : Wot;
  int kb = (ti & 15) * 64, nb = (ti >> 4) * 64;
  int r0 = t >> 4, c4 = (t & 15) * 4;
  for (int i = 0; i < 4; i++) {
    int row = r0 + i * 16;
    float4 v = *reinterpret_cast<const float4*>(W + (size_t)(kb + row) * Ee + nb + c4);
    tile[row][c4 + 0] = f2h(v.x); tile[row][c4 + 1] = f2h(v.y);
    tile[row][c4 + 2] = f2h(v.z); tile[row][c4 + 3] = f2h(v.w);
  }
  __syncthreads();
  for (int i = 0; i < 4; i++) {
    int nrow = r0 + i * 16;
    ushort4 o;
    o.x = tile[c4 + 0][nrow]; o.y = tile[c4 + 1][nrow];
    o.z = tile[c4 + 2][nrow]; o.w = tile[c4 + 3][nrow];
    *reinterpret_cast<ushort4*>(Wt + (size_t)(nb + nrow) * Ee + kb + c4) = o;
  }
}

// ---- z-fused QKV GEMM (R13): BM=128, BK=64, 512 thr, grid 256 ----
// 8 waves (wm 2 x wn 4); wave tile 64(m) x 32(n) per z. A staged once per
// K-step for 3x MFMA. bid&7 = n-panel (XCD; W panels L2-resident).
// z 0/1 (Q/K): C^T (W-frag as A-operand), half4 stores to [h][s][d];
//   Q pre-scaled by 0.125*log2e.  z 2 (V): C, writes V^T [h][d][perm(s)].
__global__ __launch_bounds__(512, 2) void k_gemm(
    const unsigned short* __restrict__ A,
    const unsigned short* __restrict__ W0, const unsigned short* __restrict__ W1,
    const unsigned short* __restrict__ W2,
    const float* __restrict__ b0, const float* __restrict__ b1, const float* __restrict__ b2,
    void* d0, void* d1, void* d2) {
  __shared__ __align__(16) unsigned short Al[2 * 8192];      // 2 x 128x64 = 32 KB
  __shared__ __align__(16) unsigned short Bl[2 * 3 * 8192];  // 2 x 3 x 128x64 = 96 KB
  int bid = blockIdx.x;
  int yp = bid & 7;   // n-panel -> XCD id
  int xm = bid >> 3;  // m-tile 0..31
  int m0 = xm * 128, n0 = yp * 128;

  int t = threadIdx.x;
  int w = t >> 6, L = t & 63, quad = L >> 4, c = L & 15;
  int wm = w >> 2, wn = w & 3;  // wave -> 64-row x 32-col subtile

  const unsigned short* Wz[3] = {W0, W1, W2};

  f32x4 zero = {0.f, 0.f, 0.f, 0.f};
  f32x4 acc[3][4][2];  // [z][m-frag a][n-frag b]
#pragma unroll
  for (int z = 0; z < 3; z++)
#pragma unroll
    for (int a = 0; a < 4; a++)
#pragma unroll
      for (int b = 0; b < 2; b++) acc[z][a][b] = zero;

  // stage one K-step: A 1024 chunks (2/thread) + 3 W tiles 1024 chunks each
  auto stageAB = [&](int buf, int k0) {
#pragma unroll
    for (int i = 0; i < 2; i++) {
      int ch = i * 512 + t;
      int row = ch >> 3, kg = (ch & 7) ^ (row & 7);
      gload16(A + (size_t)(m0 + row) * 1024 + k0 + kg * 8, &Al[buf * 8192 + ch * 8]);
    }
#pragma unroll
    for (int z = 0; z < 3; z++)
#pragma unroll
      for (int i = 0; i < 2; i++) {
        int ch = i * 512 + t;
        int row = ch >> 3, kg = (ch & 7) ^ (row & 7);
        gload16(Wz[z] + (size_t)(n0 + row) * 1024 + k0 + kg * 8,
                &Bl[(buf * 3 + z) * 8192 + ch * 8]);
      }
  };

  auto compute = [&](int cur) {
    const unsigned short* Ab = &Al[cur * 8192];
#pragma unroll
    for (int ks = 0; ks < 2; ks++) {
      half8 af[4];
#pragma unroll
      for (int a = 0; a < 4; a++) {
        int row = wm * 64 + a * 16 + c;
        int kg = (quad + 4 * ks) ^ (row & 7);
        af[a] = *reinterpret_cast<const half8*>(&Ab[row * 64 + kg * 8]);
      }
#pragma unroll
      for (int z = 0; z < 3; z++) {
        const unsigned short* Bb = &Bl[(cur * 3 + z) * 8192];
        half8 bfr[2];
#pragma unroll
        for (int b = 0; b < 2; b++) {
          int row = wn * 32 + b * 16 + c;
          int kg = (quad + 4 * ks) ^ (row & 7);
          bfr[b] = *reinterpret_cast<const half8*>(&Bb[row * 64 + kg * 8]);
        }
#pragma unroll
        for (int a = 0; a < 4; a++)
#pragma unroll
          for (int b = 0; b < 2; b++) {
            if (z < 2)  // C^T: W-frag as A-operand
              acc[z][a][b] = __builtin_amdgcn_mfma_f32_16x16x32_f16(bfr[b], af[a], acc[z][a][b], 0, 0, 0);
            else        // C: A-frag as A-operand
              acc[z][a][b] = __builtin_amdgcn_mfma_f32_16x16x32_f16(af[a], bfr[b], acc[z][a][b], 0, 0, 0);
          }
      }
    }
  };

  stageAB(0, 0);
  stageAB(1, 64);
  for (int k0 = 0; k0 < 960; k0 += 64) {
    int cur = (k0 >> 6) & 1;
    asm volatile("s_waitcnt vmcnt(8)" ::: "memory");  // cur tile landed; next in flight
    __builtin_amdgcn_s_barrier();
    __builtin_amdgcn_sched_barrier(0);
    compute(cur);
    __builtin_amdgcn_s_barrier();                     // all waves done reading buf cur
    if (k0 < 896) stageAB(cur, k0 + 128);             // overwrite with tile k+2
  }
  asm volatile("s_waitcnt vmcnt(0)" ::: "memory");    // peeled last tile (15)
  __builtin_amdgcn_s_barrier();
  __builtin_amdgcn_sched_barrier(0);
  compute(1);

  // ---- epilogues ----
  // z 0/1: C^T fragment (n-frag b, m-frag a): regs = 4 consecutive d.
  {
#pragma unroll
    for (int z = 0; z < 2; z++) {
      float sc = (z == 0) ? 0.18033688011112042f : 1.0f;
      const float* bias = (z == 0) ? b0 : b1;
      unsigned short* qk = (unsigned short*)((z == 0) ? d0 : d1);
#pragma unroll
      for (int b = 0; b < 2; b++) {
        int nb4 = n0 + wn * 32 + b * 16 + quad * 4;
        int hh = nb4 >> 6, d = nb4 & 63;
        f32x4 b4 = *reinterpret_cast<const f32x4*>(bias + nb4);
#pragma unroll
        for (int a = 0; a < 4; a++) {
          int s = m0 + wm * 64 + a * 16 + c;
          half4 hv;
#pragma unroll
          for (int r = 0; r < 4; r++) hv[r] = (_Float16)((acc[z][a][b][r] + b4[r]) * sc);
          *reinterpret_cast<half4*>(&qk[(size_t)hh * Sq * Dh + (size_t)s * Dh + d]) = hv;
        }
      }
    }
  }
  // z 2 (V): C fragment (m-frag a, n-frag b) -> V^T [h][d][perm(s)]
  {
    unsigned short* Vt = (unsigned short*)d2;
#pragma unroll
    for (int b = 0; b < 2; b++) {
      int n = n0 + wn * 32 + b * 16 + c;
      int hh = n >> 6, d = n & 63;
      float bvf = b2[n];
#pragma unroll
      for (int a = 0; a < 4; a++) {
        int pos = m0 + wm * 64 + (a >> 1) * 32 + quad * 8 + (a & 1) * 4;
        half4 hv;
#pragma unroll
        for (int r = 0; r < 4; r++) hv[r] = (_Float16)(acc[2][a][b][r] + bvf);
        *reinterpret_cast<half4*>(&Vt[(size_t)hh * Dh * Sq + (size_t)d * Sq + pos]) = hv;
      }
    }
  }
}

// ---- Output GEMM: 64x128 tiles, 1-D grid 512 (bid&7 = n-panel/XCD) ----
// C^T accumulation, coalesced float4 stores to fp32 [s][1024].
// 2-deep counted-vmcnt pipeline (6 gloads/thread per stage -> vmcnt(6)).
__global__ __launch_bounds__(256) void k_gemmO(
    const unsigned short* __restrict__ A, const unsigned short* __restrict__ Wt,
    const float* __restrict__ bias, float* __restrict__ out) {
  __shared__ __align__(16) unsigned short Al[2 * 64 * 64];   // 16 KB
  __shared__ __align__(16) unsigned short Bl[2 * 128 * 64];  // 32 KB
  int bid = blockIdx.x;
  int yp = bid & 7;
  int xm = bid >> 3;  // 64 m-tiles
  int t = threadIdx.x;
  int w = t >> 6, L = t & 63, quad = L >> 4, c = L & 15;
  int m0 = xm * 64, n0 = yp * 128;
  int wm = w & 1, wn = w >> 1;  // wave -> 32-row x 64-col subtile

  f32x4 zero = {0.f, 0.f, 0.f, 0.f};
  f32x4 acc[4][2];
#pragma unroll
  for (int j = 0; j < 4; j++)
#pragma unroll
    for (int i = 0; i < 2; i++) acc[j][i] = zero;

  auto stageAB = [&](int buf, int k0) {
#pragma unroll
    for (int i = 0; i < 2; i++) {  // A tile 64x64: 512 chunks
      int ch = i * 256 + t;
      int row = ch >> 3, kg = (ch & 7) ^ (row & 7);
      gload16(A + (size_t)(m0 + row) * 1024 + k0 + kg * 8, &Al[buf * 4096 + ch * 8]);
    }
#pragma unroll
    for (int i = 0; i < 4; i++) {  // B tile 128x64: 1024 chunks
      int ch = i * 256 + t;
      int row = ch >> 3, kg = (ch & 7) ^ (row & 7);
      gload16(Wt + (size_t)(n0 + row) * 1024 + k0 + kg * 8, &Bl[buf * 8192 + ch * 8]);
    }
  };
  auto compute = [&](int cur) {
    const unsigned short* Ab = &Al[cur * 4096];
    const unsigned short* Bb = &Bl[cur * 8192];
#pragma unroll
    for (int ks = 0; ks < 2; ks++) {
      half8 af[2], bfr[4];
#pragma unroll
      for (int i = 0; i < 2; i++) {
        int row = wm * 32 + i * 16 + c;
        int kg = (quad + 4 * ks) ^ (row & 7);
        af[i] = *reinterpret_cast<const half8*>(&Ab[row * 64 + kg * 8]);
      }
#pragma unroll
      for (int j = 0; j < 4; j++) {
        int row = wn * 64 + j * 16 + c;
        int kg = (quad + 4 * ks) ^ (row & 7);
        bfr[j] = *reinterpret_cast<const half8*>(&Bb[row * 64 + kg * 8]);
      }
#pragma unroll
      for (int j = 0; j < 4; j++)
#pragma unroll
        for (int i = 0; i < 2; i++)
          acc[j][i] = __builtin_amdgcn_mfma_f32_16x16x32_f16(bfr[j], af[i], acc[j][i], 0, 0, 0);
    }
  };
  stageAB(0, 0);
  stageAB(1, 64);
  for (int k0 = 0; k0 < 960; k0 += 64) {
    int cur = (k0 >> 6) & 1;
    asm volatile("s_waitcnt vmcnt(6)" ::: "memory");
    __builtin_amdgcn_s_barrier();
    __builtin_amdgcn_sched_barrier(0);
    compute(cur);
    __builtin_amdgcn_s_barrier();
    if (k0 < 896) stageAB(cur, k0 + 128);
  }
  asm volatile("s_waitcnt vmcnt(0)" ::: "memory");
  __builtin_amdgcn_s_barrier();
  __builtin_amdgcn_sched_barrier(0);
  compute(1);

#pragma unroll
  for (int j = 0; j < 4; j++) {
    int nb4 = n0 + wn * 64 + j * 16 + quad * 4;
    f32x4 b4 = *reinterpret_cast<const f32x4*>(bias + nb4);
#pragma unroll
    for (int i = 0; i < 2; i++) {
      int s = m0 + wm * 32 + i * 16 + c;
      f32x4 v = acc[j][i] + b4;
      *reinterpret_cast<f32x4*>(out + (size_t)s * 1024 + nb4) = v;
    }
  }
}

// ---- flash attention, S^T/O^T form, all-K=32 MFMA, key-parity waves ----
// Q,K [h][s][64] f16 (Q pre-scaled), Vt [h][64][perm(s)] f16 -> O [s][1024] f16
// 256 threads = 4 waves; wave w: parity par=w>>1 (even/odd key tiles),
// wl=w&1 owns 64 q-rows (qg=4). Grid (32,16) = 512 blocks = 2/CU.
// LDS: [buf][Kev,Kod,Vev,Vod][8KB] = 64KB. Body = R9 form (QK half-passes).
__global__ __launch_bounds__(256, 2) void k_attn(
    const unsigned short* __restrict__ Q, const unsigned short* __restrict__ K,
    const unsigned short* __restrict__ Vt, unsigned short* __restrict__ O) {
  __shared__ __align__(16) unsigned short SM[32768];  // 64 KB
  int t = threadIdx.x;
  int w = t >> 6, L = t & 63, quad = L >> 4, c = L & 15;
  int wl = w & 1, par = w >> 1;
  int h = blockIdx.y, qb = blockIdx.x;
  const unsigned short* Qh = Q + (size_t)h * Sq * Dh;
  const unsigned short* Kh = K + (size_t)h * Sq * Dh;
  const unsigned short* Vth = Vt + (size_t)h * Dh * Sq;

  half8 qf[4][2];
#pragma unroll
  for (int qg = 0; qg < 4; qg++) {
    int qrow = qb * 128 + wl * 64 + qg * 16 + c;
#pragma unroll
    for (int ks = 0; ks < 2; ks++)
      qf[qg][ks] = *reinterpret_cast<const half8*>(Qh + (size_t)qrow * Dh + ks * 32 + quad * 8);
  }

  f32x4 zero = {0.f, 0.f, 0.f, 0.f};
  f32x4 o[4][4];
  f32x4 l[4];
#pragma unroll
  for (int qg = 0; qg < 4; qg++) {
    l[qg] = zero;
#pragma unroll
    for (int dt = 0; dt < 4; dt++) o[qg][dt] = zero;
  }
  half8 ones8;
#pragma unroll
  for (int j = 0; j < 8; j++) ones8[j] = (_Float16)1.0f;

  int koff[2][4], voff[4][2];
#pragma unroll
  for (int ks = 0; ks < 2; ks++)
#pragma unroll
    for (int nt = 0; nt < 4; nt++) {
      int row = nt * 16 + c;
      koff[ks][nt] = par * 4096 + row * 64 + (((ks * 4 + quad) ^ (row & 7)) * 8);
    }
#pragma unroll
  for (int dt = 0; dt < 4; dt++)
#pragma unroll
    for (int n2 = 0; n2 < 2; n2++) {
      int row = dt * 16 + c;
      voff[dt][n2] = (2 + par) * 4096 + row * 64 + (((n2 * 4 + quad) ^ (row & 7)) * 8);
    }

  // staging bases: 256 threads cover a 512-chunk (8 KB) tile in 2 chunks each
  const unsigned short* KgB[2];
  const unsigned short* VgB[2];
#pragma unroll
  for (int i = 0; i < 2; i++) {
    int ch = i * 256 + t;
    int row = ch >> 3, kg = (ch & 7) ^ (row & 7);
    KgB[i] = Kh + row * Dh + kg * 8;           // + tb*4096
    VgB[i] = Vth + (size_t)row * Sq + kg * 8;  // + tb*64
  }

  auto stage = [&](int bufo, int tb) {
#pragma unroll
    for (int p2 = 0; p2 < 2; p2++) {
#pragma unroll
      for (int i = 0; i < 2; i++)
        gload16(KgB[i] + (size_t)(tb + p2) * 4096, &SM[bufo + p2 * 4096 + (i * 256 + t) * 8]);
#pragma unroll
      for (int i = 0; i < 2; i++)
        gload16(VgB[i] + (size_t)(tb + p2) * 64, &SM[bufo + (2 + p2) * 4096 + (i * 256 + t) * 8]);
    }
  };

  stage(0, 0);

  auto body = [&](int BUFOFF) {
    half8 pB[4][2];
    // QK^T + exp in two 2-qg half-passes (caps st live range at 8 f32x4).
    // ks=0 MFMAs use zero as C operand (no per-body acc zero-init movs).
#pragma unroll
    for (int h2 = 0; h2 < 2; h2++) {
      f32x4 st[2][4];
      __builtin_amdgcn_s_setprio(1);
#pragma unroll
      for (int nt = 0; nt < 4; nt++) {
        half8 kfv = *reinterpret_cast<const half8*>(&SM[koff[0][nt] + BUFOFF]);
        st[0][nt] = __builtin_amdgcn_mfma_f32_16x16x32_f16(kfv, qf[2 * h2 + 0][0], zero, 0, 0, 0);
        st[1][nt] = __builtin_amdgcn_mfma_f32_16x16x32_f16(kfv, qf[2 * h2 + 1][0], zero, 0, 0, 0);
      }
#pragma unroll
      for (int nt = 0; nt < 4; nt++) {
        half8 kfv = *reinterpret_cast<const half8*>(&SM[koff[1][nt] + BUFOFF]);
        st[0][nt] = __builtin_amdgcn_mfma_f32_16x16x32_f16(kfv, qf[2 * h2 + 0][1], st[0][nt], 0, 0, 0);
        st[1][nt] = __builtin_amdgcn_mfma_f32_16x16x32_f16(kfv, qf[2 * h2 + 1][1], st[1][nt], 0, 0, 0);
      }
      __builtin_amdgcn_s_setprio(0);
#pragma unroll
      for (int q2 = 0; q2 < 2; q2++)
#pragma unroll
        for (int n2 = 0; n2 < 2; n2++) {
          U8 u;
          u.h2[0] = pk(__builtin_amdgcn_exp2f(st[q2][2 * n2][0]), __builtin_amdgcn_exp2f(st[q2][2 * n2][1]));
          u.h2[1] = pk(__builtin_amdgcn_exp2f(st[q2][2 * n2][2]), __builtin_amdgcn_exp2f(st[q2][2 * n2][3]));
          u.h2[2] = pk(__builtin_amdgcn_exp2f(st[q2][2 * n2 + 1][0]), __builtin_amdgcn_exp2f(st[q2][2 * n2 + 1][1]));
          u.h2[3] = pk(__builtin_amdgcn_exp2f(st[q2][2 * n2 + 1][2]), __builtin_amdgcn_exp2f(st[q2][2 * n2 + 1][3]));
          pB[2 * h2 + q2][n2] = u.v8;
          l[2 * h2 + q2] = __builtin_amdgcn_mfma_f32_16x16x32_f16(ones8, u.v8, l[2 * h2 + q2], 0, 0, 0);
        }
    }
    // PV: read each V fragment once, feed all 4 qg
    __builtin_amdgcn_s_setprio(1);
#pragma unroll
    for (int dt = 0; dt < 4; dt++)
#pragma unroll
      for (int n2 = 0; n2 < 2; n2++) {
        half8 vv = *reinterpret_cast<const half8*>(&SM[voff[dt][n2] + BUFOFF]);
        o[0][dt] = __builtin_amdgcn_mfma_f32_16x16x32_f16(vv, pB[0][n2], o[0][dt], 0, 0, 0);
        o[1][dt] = __builtin_amdgcn_mfma_f32_16x16x32_f16(vv, pB[1][n2], o[1][dt], 0, 0, 0);
        o[2][dt] = __builtin_amdgcn_mfma_f32_16x16x32_f16(vv, pB[2][n2], o[2][dt], 0, 0, 0);
        o[3][dt] = __builtin_amdgcn_mfma_f32_16x16x32_f16(vv, pB[3][n2], o[3][dt], 0, 0, 0);
      }
    __builtin_amdgcn_s_setprio(0);
  };

  for (int ob2 = 0; ob2 < 16; ob2++) {
    __syncthreads();
    stage(16384, 4 * ob2 + 2);
    body(0);
    __syncthreads();
    if (ob2 < 15) stage(0, 4 * ob2 + 4);
    body(16384);
  }

  // combine even/odd partials: plain sums -> exact addition.
  // per wl: 16 o-vecs + 1 packed-l vec = 17 vecs x 64 lanes x 16 B; 2 wl = 34 KB.
  __syncthreads();
  float* cb = (float*)SM;
  if (par == 1) {
#pragma unroll
    for (int qg = 0; qg < 4; qg++)
#pragma unroll
      for (int dt = 0; dt < 4; dt++)
        *reinterpret_cast<f32x4*>(cb + ((wl * 17 + qg * 4 + dt) * 64 + L) * 4) = o[qg][dt];
    f32x4 lv = {l[0][0], l[1][0], l[2][0], l[3][0]};
    *reinterpret_cast<f32x4*>(cb + ((wl * 17 + 16) * 64 + L) * 4) = lv;
  }
  __syncthreads();
  if (par == 0) {
#pragma unroll
    for (int qg = 0; qg < 4; qg++)
#pragma unroll
      for (int dt = 0; dt < 4; dt++)
        o[qg][dt] += *reinterpret_cast<const f32x4*>(cb + ((wl * 17 + qg * 4 + dt) * 64 + L) * 4);
    f32x4 lv = *reinterpret_cast<const f32x4*>(cb + ((wl * 17 + 16) * 64 + L) * 4);
#pragma unroll
    for (int qg = 0; qg < 4; qg++) {
      float inv = 1.f / (l[qg][0] + lv[qg]);
      int q = qb * 128 + wl * 64 + qg * 16 + c;
#pragma unroll
      for (int dt = 0; dt < 4; dt++) {
        half4 hv;
#pragma unroll
        for (int r = 0; r < 4; r++) hv[r] = (_Float16)(o[qg][dt][r] * inv);
        *reinterpret_cast<half4*>(&O[(size_t)q * 1024 + h * 64 + dt * 16 + quad * 4]) = hv;
      }
    }
  }
}

extern "C" void kernel_launch(void* const* d_in, const int* in_sizes, int n_in,
                              void* d_out, int out_size, void* d_ws, size_t ws_size,
                              hipStream_t stream) {
  const float* x  = (const float*)d_in[0];
  const float* Wq = (const float*)d_in[1];
  const float* bq = (const float*)d_in[2];
  const float* Wk = (const float*)d_in[3];
  const float* bk = (const float*)d_in[4];
  const float* Wv = (const float*)d_in[5];
  const float* bv = (const float*)d_in[6];
  const float* Wo = (const float*)d_in[7];
  const float* bo = (const float*)d_in[8];

  char* ws = (char*)d_ws;
  const size_t MB = 1u << 20;
  unsigned short* xb  = (unsigned short*)(ws);            // 8 MB  x as f16
  unsigned short* Wqt = (unsigned short*)(ws + 8 * MB);   // 2 MB each, transposed f16
  unsigned short* Wkt = (unsigned short*)(ws + 10 * MB);
  unsigned short* Wvt = (unsigned short*)(ws + 12 * MB);
  unsigned short* Wot = (unsigned short*)(ws + 14 * MB);
  unsigned short* Qb  = (unsigned short*)(ws + 16 * MB);  // 8 MB [h][s][d]
  unsigned short* Kb  = (unsigned short*)(ws + 24 * MB);  // 8 MB [h][s][d]
  unsigned short* Vtg = (unsigned short*)(ws + 32 * MB);  // 8 MB [h][d][perm(s)]
  unsigned short* Ob  = (unsigned short*)(ws + 40 * MB);  // 8 MB [s][e]  (total 48 MB)

  k_prep<<<5120, 256, 0, stream>>>(x, Wq, Wk, Wv, Wo, xb, Wqt, Wkt, Wvt, Wot);
  // ATTRIBUTION: k_gemm launched 3x (idempotent). dur_us - 212.6 = 2*t_gemm.
  k_gemm<<<256, 512, 0, stream>>>(xb, Wqt, Wkt, Wvt, bq, bk, bv,
                                  (void*)Qb, (void*)Kb, (void*)Vtg);
  k_gemm<<<256, 512, 0, stream>>>(xb, Wqt, Wkt, Wvt, bq, bk, bv,
                                  (void*)Qb, (void*)Kb, (void*)Vtg);
  k_gemm<<<256, 512, 0, stream>>>(xb, Wqt, Wkt, Wvt, bq, bk, bv,
                                  (void*)Qb, (void*)Kb, (void*)Vtg);
  k_attn<<<dim3(32, 16), 256, 0, stream>>>(Qb, Kb, Vtg, Ob);
  k_gemmO<<<512, 256, 0, stream>>>(Ob, Wot, bo, (float*)d_out);
}

// Round 12
// 262.114 us; speedup vs baseline: 1.0472x; 1.0472x over previous
//
#include <hip/hip_runtime.h>

// MultiHeadedAttention: B=1, S=4096, E=1024, H=16, D=64, fp32 in/out.
// R19: ATTRIBUTION COMPLETION. R18 measured t_gemm = 31us (274.5-212.6)/2;
//   attn = 74.4 -> 107us unattributed across prep + gemmO + dispatch
//   overhead. This round: gemm back to 1x, prep 3x + gemmO 3x (both
//   idempotent): dur - 212.6 = 2*(t_prep + t_gemmO) closes the budget.
//   Branch A (dur ~235-245): gaps ~85us are harness-fixed -> optimize
//   gemm/attn only. Branch B (dur >= 280): a fat kernel, counters follow.
// KNOWN: t_gemm = 31us (832 TF, m97-structure level); t_attn = 74.4us
//   (~1.03 PF eff; MFMA floor ~33us; 3 overlap fixes failed).
// NOTE (R8):  cross-body software pipelining of attn spills to scratch.
// NOTE (R10): in-wave VALU/MFMA interleave pinning regresses.
// NOTE (R12/R14): GEMM latency pipelining / XCD swizzle / occupancy ~neutral.
// NOTE (R16/R17): cross-kernel fusion dead: hand-rolled barrier races
//   (XCD L2 non-coherence), cooperative launch breaks graph capture.

constexpr int Sq = 4096;
constexpr int Ee = 1024;
constexpr int Hh = 16;
constexpr int Dh = 64;

typedef _Float16 half8 __attribute__((ext_vector_type(8)));
typedef _Float16 half4 __attribute__((ext_vector_type(4)));
typedef _Float16 half2t __attribute__((ext_vector_type(2)));
typedef float f32x4 __attribute__((ext_vector_type(4)));

union U8 { half8 v8; half2t h2[4]; };

__device__ __forceinline__ unsigned short f2h(float f) {
  _Float16 h = (_Float16)f;
  return *reinterpret_cast<unsigned short*>(&h);
}

__device__ __forceinline__ half2t pk(float a, float b) {
  return __builtin_bit_cast(half2t, __builtin_amdgcn_cvt_pkrtz(a, b));
}

__device__ __forceinline__ void gload16(const void* g, void* l) {
  __builtin_amdgcn_global_load_lds(
      (const __attribute__((address_space(1))) void*)g,
      (__attribute__((address_space(3))) void*)l, 16, 0, 0);
}

// ---- fused prep: x fp32->f16 (blocks 0..4095) + 4 weight transposes ----
__global__ void k_prep(const float* __restrict__ x,
                       const float* __restrict__ Wq, const float* __restrict__ Wk,
                       const float* __restrict__ Wv, const float* __restrict__ Wo,
                       unsigned short* __restrict__ xb,
                       unsigned short* __restrict__ Wqt, unsigned short* __restrict__ Wkt,
                       unsigned short* __restrict__ Wvt, unsigned short* __restrict__ Wot) {
  int b = blockIdx.x, t = threadIdx.x;
  if (b < 4096) {
    int i = b * 256 + t;
    float4 v = reinterpret_cast<const float4*>(x)[i];
    ushort4 o;
    o.x = f2h(v.x); o.y = f2h(v.y); o.z = f2h(v.z); o.w = f2h(v.w);
    reinterpret_cast<ushort4*>(xb)[i] = o;
    return;
  }
  __shared__ unsigned short tile[64][65];
  int r = b - 4096;
  int wi = r >> 8, ti = r & 255;
  const float* W = (wi == 0) ? Wq : (wi == 1) ? Wk : (wi == 2) ? Wv : Wo;
  unsigned short* Wt = (wi == 0) ? Wqt : (wi == 1) ? Wkt : (wi == 2) ? Wvt : Wot;
  int kb = (ti & 15) * 64, nb = (ti >> 4) * 64;
  int r0 = t >> 4, c4 = (t & 15) * 4;
  for (int i = 0; i < 4; i++) {
    int row = r0 + i * 16;
    float4 v = *reinterpret_cast<const float4*>(W + (size_t)(kb + row) * Ee + nb + c4);
    tile[row][c4 + 0] = f2h(v.x); tile[row][c4 + 1] = f2h(v.y);
    tile[row][c4 + 2] = f2h(v.z); tile[row][c4 + 3] = f2h(v.w);
  }
  __syncthreads();
  for (int i = 0; i < 4; i++) {
    int nrow = r0 + i * 16;
    ushort4 o;
    o.x = tile[c4 + 0][nrow]; o.y = tile[c4 + 1][nrow];
    o.z = tile[c4 + 2][nrow]; o.w = tile[c4 + 3][nrow];
    *reinterpret_cast<ushort4*>(Wt + (size_t)(nb + nrow) * Ee + kb + c4) = o;
  }
}

// ---- z-fused QKV GEMM (R13): BM=128, BK=64, 512 thr, grid 256 ----
// 8 waves (wm 2 x wn 4); wave tile 64(m) x 32(n) per z. A staged once per
// K-step for 3x MFMA. bid&7 = n-panel (XCD; W panels L2-resident).
// z 0/1 (Q/K): C^T (W-frag as A-operand), half4 stores to [h][s][d];
//   Q pre-scaled by 0.125*log2e.  z 2 (V): C, writes V^T [h][d][perm(s)].
__global__ __launch_bounds__(512, 2) void k_gemm(
    const unsigned short* __restrict__ A,
    const unsigned short* __restrict__ W0, const unsigned short* __restrict__ W1,
    const unsigned short* __restrict__ W2,
    const float* __restrict__ b0, const float* __restrict__ b1, const float* __restrict__ b2,
    void* d0, void* d1, void* d2) {
  __shared__ __align__(16) unsigned short Al[2 * 8192];      // 2 x 128x64 = 32 KB
  __shared__ __align__(16) unsigned short Bl[2 * 3 * 8192];  // 2 x 3 x 128x64 = 96 KB
  int bid = blockIdx.x;
  int yp = bid & 7;   // n-panel -> XCD id
  int xm = bid >> 3;  // m-tile 0..31
  int m0 = xm * 128, n0 = yp * 128;

  int t = threadIdx.x;
  int w = t >> 6, L = t & 63, quad = L >> 4, c = L & 15;
  int wm = w >> 2, wn = w & 3;  // wave -> 64-row x 32-col subtile

  const unsigned short* Wz[3] = {W0, W1, W2};

  f32x4 zero = {0.f, 0.f, 0.f, 0.f};
  f32x4 acc[3][4][2];  // [z][m-frag a][n-frag b]
#pragma unroll
  for (int z = 0; z < 3; z++)
#pragma unroll
    for (int a = 0; a < 4; a++)
#pragma unroll
      for (int b = 0; b < 2; b++) acc[z][a][b] = zero;

  // stage one K-step: A 1024 chunks (2/thread) + 3 W tiles 1024 chunks each
  auto stageAB = [&](int buf, int k0) {
#pragma unroll
    for (int i = 0; i < 2; i++) {
      int ch = i * 512 + t;
      int row = ch >> 3, kg = (ch & 7) ^ (row & 7);
      gload16(A + (size_t)(m0 + row) * 1024 + k0 + kg * 8, &Al[buf * 8192 + ch * 8]);
    }
#pragma unroll
    for (int z = 0; z < 3; z++)
#pragma unroll
      for (int i = 0; i < 2; i++) {
        int ch = i * 512 + t;
        int row = ch >> 3, kg = (ch & 7) ^ (row & 7);
        gload16(Wz[z] + (size_t)(n0 + row) * 1024 + k0 + kg * 8,
                &Bl[(buf * 3 + z) * 8192 + ch * 8]);
      }
  };

  auto compute = [&](int cur) {
    const unsigned short* Ab = &Al[cur * 8192];
#pragma unroll
    for (int ks = 0; ks < 2; ks++) {
      half8 af[4];
#pragma unroll
      for (int a = 0; a < 4; a++) {
        int row = wm * 64 + a * 16 + c;
        int kg = (quad + 4 * ks) ^ (row & 7);
        af[a] = *reinterpret_cast<const half8*>(&Ab[row * 64 + kg * 8]);
      }
#pragma unroll
      for (int z = 0; z < 3; z++) {
        const unsigned short* Bb = &Bl[(cur * 3 + z) * 8192];
        half8 bfr[2];
#pragma unroll
        for (int b = 0; b < 2; b++) {
          int row = wn * 32 + b * 16 + c;
          int kg = (quad + 4 * ks) ^ (row & 7);
          bfr[b] = *reinterpret_cast<const half8*>(&Bb[row * 64 + kg * 8]);
        }
#pragma unroll
        for (int a = 0; a < 4; a++)
#pragma unroll
          for (int b = 0; b < 2; b++) {
            if (z < 2)  // C^T: W-frag as A-operand
              acc[z][a][b] = __builtin_amdgcn_mfma_f32_16x16x32_f16(bfr[b], af[a], acc[z][a][b], 0, 0, 0);
            else        // C: A-frag as A-operand
              acc[z][a][b] = __builtin_amdgcn_mfma_f32_16x16x32_f16(af[a], bfr[b], acc[z][a][b], 0, 0, 0);
          }
      }
    }
  };

  stageAB(0, 0);
  stageAB(1, 64);
  for (int k0 = 0; k0 < 960; k0 += 64) {
    int cur = (k0 >> 6) & 1;
    asm volatile("s_waitcnt vmcnt(8)" ::: "memory");  // cur tile landed; next in flight
    __builtin_amdgcn_s_barrier();
    __builtin_amdgcn_sched_barrier(0);
    compute(cur);
    __builtin_amdgcn_s_barrier();                     // all waves done reading buf cur
    if (k0 < 896) stageAB(cur, k0 + 128);             // overwrite with tile k+2
  }
  asm volatile("s_waitcnt vmcnt(0)" ::: "memory");    // peeled last tile (15)
  __builtin_amdgcn_s_barrier();
  __builtin_amdgcn_sched_barrier(0);
  compute(1);

  // ---- epilogues ----
  // z 0/1: C^T fragment (n-frag b, m-frag a): regs = 4 consecutive d.
  {
#pragma unroll
    for (int z = 0; z < 2; z++) {
      float sc = (z == 0) ? 0.18033688011112042f : 1.0f;
      const float* bias = (z == 0) ? b0 : b1;
      unsigned short* qk = (unsigned short*)((z == 0) ? d0 : d1);
#pragma unroll
      for (int b = 0; b < 2; b++) {
        int nb4 = n0 + wn * 32 + b * 16 + quad * 4;
        int hh = nb4 >> 6, d = nb4 & 63;
        f32x4 b4 = *reinterpret_cast<const f32x4*>(bias + nb4);
#pragma unroll
        for (int a = 0; a < 4; a++) {
          int s = m0 + wm * 64 + a * 16 + c;
          half4 hv;
#pragma unroll
          for (int r = 0; r < 4; r++) hv[r] = (_Float16)((acc[z][a][b][r] + b4[r]) * sc);
          *reinterpret_cast<half4*>(&qk[(size_t)hh * Sq * Dh + (size_t)s * Dh + d]) = hv;
        }
      }
    }
  }
  // z 2 (V): C fragment (m-frag a, n-frag b) -> V^T [h][d][perm(s)]
  {
    unsigned short* Vt = (unsigned short*)d2;
#pragma unroll
    for (int b = 0; b < 2; b++) {
      int n = n0 + wn * 32 + b * 16 + c;
      int hh = n >> 6, d = n & 63;
      float bvf = b2[n];
#pragma unroll
      for (int a = 0; a < 4; a++) {
        int pos = m0 + wm * 64 + (a >> 1) * 32 + quad * 8 + (a & 1) * 4;
        half4 hv;
#pragma unroll
        for (int r = 0; r < 4; r++) hv[r] = (_Float16)(acc[2][a][b][r] + bvf);
        *reinterpret_cast<half4*>(&Vt[(size_t)hh * Dh * Sq + (size_t)d * Sq + pos]) = hv;
      }
    }
  }
}

// ---- Output GEMM: 64x128 tiles, 1-D grid 512 (bid&7 = n-panel/XCD) ----
// C^T accumulation, coalesced float4 stores to fp32 [s][1024].
// 2-deep counted-vmcnt pipeline (6 gloads/thread per stage -> vmcnt(6)).
__global__ __launch_bounds__(256) void k_gemmO(
    const unsigned short* __restrict__ A, const unsigned short* __restrict__ Wt,
    const float* __restrict__ bias, float* __restrict__ out) {
  __shared__ __align__(16) unsigned short Al[2 * 64 * 64];   // 16 KB
  __shared__ __align__(16) unsigned short Bl[2 * 128 * 64];  // 32 KB
  int bid = blockIdx.x;
  int yp = bid & 7;
  int xm = bid >> 3;  // 64 m-tiles
  int t = threadIdx.x;
  int w = t >> 6, L = t & 63, quad = L >> 4, c = L & 15;
  int m0 = xm * 64, n0 = yp * 128;
  int wm = w & 1, wn = w >> 1;  // wave -> 32-row x 64-col subtile

  f32x4 zero = {0.f, 0.f, 0.f, 0.f};
  f32x4 acc[4][2];
#pragma unroll
  for (int j = 0; j < 4; j++)
#pragma unroll
    for (int i = 0; i < 2; i++) acc[j][i] = zero;

  auto stageAB = [&](int buf, int k0) {
#pragma unroll
    for (int i = 0; i < 2; i++) {  // A tile 64x64: 512 chunks
      int ch = i * 256 + t;
      int row = ch >> 3, kg = (ch & 7) ^ (row & 7);
      gload16(A + (size_t)(m0 + row) * 1024 + k0 + kg * 8, &Al[buf * 4096 + ch * 8]);
    }
#pragma unroll
    for (int i = 0; i < 4; i++) {  // B tile 128x64: 1024 chunks
      int ch = i * 256 + t;
      int row = ch >> 3, kg = (ch & 7) ^ (row & 7);
      gload16(Wt + (size_t)(n0 + row) * 1024 + k0 + kg * 8, &Bl[buf * 8192 + ch * 8]);
    }
  };
  auto compute = [&](int cur) {
    const unsigned short* Ab = &Al[cur * 4096];
    const unsigned short* Bb = &Bl[cur * 8192];
#pragma unroll
    for (int ks = 0; ks < 2; ks++) {
      half8 af[2], bfr[4];
#pragma unroll
      for (int i = 0; i < 2; i++) {
        int row = wm * 32 + i * 16 + c;
        int kg = (quad + 4 * ks) ^ (row & 7);
        af[i] = *reinterpret_cast<const half8*>(&Ab[row * 64 + kg * 8]);
      }
#pragma unroll
      for (int j = 0; j < 4; j++) {
        int row = wn * 64 + j * 16 + c;
        int kg = (quad + 4 * ks) ^ (row & 7);
        bfr[j] = *reinterpret_cast<const half8*>(&Bb[row * 64 + kg * 8]);
      }
#pragma unroll
      for (int j = 0; j < 4; j++)
#pragma unroll
        for (int i = 0; i < 2; i++)
          acc[j][i] = __builtin_amdgcn_mfma_f32_16x16x32_f16(bfr[j], af[i], acc[j][i], 0, 0, 0);
    }
  };
  stageAB(0, 0);
  stageAB(1, 64);
  for (int k0 = 0; k0 < 960; k0 += 64) {
    int cur = (k0 >> 6) & 1;
    asm volatile("s_waitcnt vmcnt(6)" ::: "memory");
    __builtin_amdgcn_s_barrier();
    __builtin_amdgcn_sched_barrier(0);
    compute(cur);
    __builtin_amdgcn_s_barrier();
    if (k0 < 896) stageAB(cur, k0 + 128);
  }
  asm volatile("s_waitcnt vmcnt(0)" ::: "memory");
  __builtin_amdgcn_s_barrier();
  __builtin_amdgcn_sched_barrier(0);
  compute(1);

#pragma unroll
  for (int j = 0; j < 4; j++) {
    int nb4 = n0 + wn * 64 + j * 16 + quad * 4;
    f32x4 b4 = *reinterpret_cast<const f32x4*>(bias + nb4);
#pragma unroll
    for (int i = 0; i < 2; i++) {
      int s = m0 + wm * 32 + i * 16 + c;
      f32x4 v = acc[j][i] + b4;
      *reinterpret_cast<f32x4*>(out + (size_t)s * 1024 + nb4) = v;
    }
  }
}

// ---- flash attention, S^T/O^T form, all-K=32 MFMA, key-parity waves ----
// Q,K [h][s][64] f16 (Q pre-scaled), Vt [h][64][perm(s)] f16 -> O [s][1024] f16
// 256 threads = 4 waves; wave w: parity par=w>>1 (even/odd key tiles),
// wl=w&1 owns 64 q-rows (qg=4). Grid (32,16) = 512 blocks = 2/CU.
// LDS: [buf][Kev,Kod,Vev,Vod][8KB] = 64KB. Body = R9 form (QK half-passes).
__global__ __launch_bounds__(256, 2) void k_attn(
    const unsigned short* __restrict__ Q, const unsigned short* __restrict__ K,
    const unsigned short* __restrict__ Vt, unsigned short* __restrict__ O) {
  __shared__ __align__(16) unsigned short SM[32768];  // 64 KB
  int t = threadIdx.x;
  int w = t >> 6, L = t & 63, quad = L >> 4, c = L & 15;
  int wl = w & 1, par = w >> 1;
  int h = blockIdx.y, qb = blockIdx.x;
  const unsigned short* Qh = Q + (size_t)h * Sq * Dh;
  const unsigned short* Kh = K + (size_t)h * Sq * Dh;
  const unsigned short* Vth = Vt + (size_t)h * Dh * Sq;

  half8 qf[4][2];
#pragma unroll
  for (int qg = 0; qg < 4; qg++) {
    int qrow = qb * 128 + wl * 64 + qg * 16 + c;
#pragma unroll
    for (int ks = 0; ks < 2; ks++)
      qf[qg][ks] = *reinterpret_cast<const half8*>(Qh + (size_t)qrow * Dh + ks * 32 + quad * 8);
  }

  f32x4 zero = {0.f, 0.f, 0.f, 0.f};
  f32x4 o[4][4];
  f32x4 l[4];
#pragma unroll
  for (int qg = 0; qg < 4; qg++) {
    l[qg] = zero;
#pragma unroll
    for (int dt = 0; dt < 4; dt++) o[qg][dt] = zero;
  }
  half8 ones8;
#pragma unroll
  for (int j = 0; j < 8; j++) ones8[j] = (_Float16)1.0f;

  int koff[2][4], voff[4][2];
#pragma unroll
  for (int ks = 0; ks < 2; ks++)
#pragma unroll
    for (int nt = 0; nt < 4; nt++) {
      int row = nt * 16 + c;
      koff[ks][nt] = par * 4096 + row * 64 + (((ks * 4 + quad) ^ (row & 7)) * 8);
    }
#pragma unroll
  for (int dt = 0; dt < 4; dt++)
#pragma unroll
    for (int n2 = 0; n2 < 2; n2++) {
      int row = dt * 16 + c;
      voff[dt][n2] = (2 + par) * 4096 + row * 64 + (((n2 * 4 + quad) ^ (row & 7)) * 8);
    }

  // staging bases: 256 threads cover a 512-chunk (8 KB) tile in 2 chunks each
  const unsigned short* KgB[2];
  const unsigned short* VgB[2];
#pragma unroll
  for (int i = 0; i < 2; i++) {
    int ch = i * 256 + t;
    int row = ch >> 3, kg = (ch & 7) ^ (row & 7);
    KgB[i] = Kh + row * Dh + kg * 8;           // + tb*4096
    VgB[i] = Vth + (size_t)row * Sq + kg * 8;  // + tb*64
  }

  auto stage = [&](int bufo, int tb) {
#pragma unroll
    for (int p2 = 0; p2 < 2; p2++) {
#pragma unroll
      for (int i = 0; i < 2; i++)
        gload16(KgB[i] + (size_t)(tb + p2) * 4096, &SM[bufo + p2 * 4096 + (i * 256 + t) * 8]);
#pragma unroll
      for (int i = 0; i < 2; i++)
        gload16(VgB[i] + (size_t)(tb + p2) * 64, &SM[bufo + (2 + p2) * 4096 + (i * 256 + t) * 8]);
    }
  };

  stage(0, 0);

  auto body = [&](int BUFOFF) {
    half8 pB[4][2];
    // QK^T + exp in two 2-qg half-passes (caps st live range at 8 f32x4).
    // ks=0 MFMAs use zero as C operand (no per-body acc zero-init movs).
#pragma unroll
    for (int h2 = 0; h2 < 2; h2++) {
      f32x4 st[2][4];
      __builtin_amdgcn_s_setprio(1);
#pragma unroll
      for (int nt = 0; nt < 4; nt++) {
        half8 kfv = *reinterpret_cast<const half8*>(&SM[koff[0][nt] + BUFOFF]);
        st[0][nt] = __builtin_amdgcn_mfma_f32_16x16x32_f16(kfv, qf[2 * h2 + 0][0], zero, 0, 0, 0);
        st[1][nt] = __builtin_amdgcn_mfma_f32_16x16x32_f16(kfv, qf[2 * h2 + 1][0], zero, 0, 0, 0);
      }
#pragma unroll
      for (int nt = 0; nt < 4; nt++) {
        half8 kfv = *reinterpret_cast<const half8*>(&SM[koff[1][nt] + BUFOFF]);
        st[0][nt] = __builtin_amdgcn_mfma_f32_16x16x32_f16(kfv, qf[2 * h2 + 0][1], st[0][nt], 0, 0, 0);
        st[1][nt] = __builtin_amdgcn_mfma_f32_16x16x32_f16(kfv, qf[2 * h2 + 1][1], st[1][nt], 0, 0, 0);
      }
      __builtin_amdgcn_s_setprio(0);
#pragma unroll
      for (int q2 = 0; q2 < 2; q2++)
#pragma unroll
        for (int n2 = 0; n2 < 2; n2++) {
          U8 u;
          u.h2[0] = pk(__builtin_amdgcn_exp2f(st[q2][2 * n2][0]), __builtin_amdgcn_exp2f(st[q2][2 * n2][1]));
          u.h2[1] = pk(__builtin_amdgcn_exp2f(st[q2][2 * n2][2]), __builtin_amdgcn_exp2f(st[q2][2 * n2][3]));
          u.h2[2] = pk(__builtin_amdgcn_exp2f(st[q2][2 * n2 + 1][0]), __builtin_amdgcn_exp2f(st[q2][2 * n2 + 1][1]));
          u.h2[3] = pk(__builtin_amdgcn_exp2f(st[q2][2 * n2 + 1][2]), __builtin_amdgcn_exp2f(st[q2][2 * n2 + 1][3]));
          pB[2 * h2 + q2][n2] = u.v8;
          l[2 * h2 + q2] = __builtin_amdgcn_mfma_f32_16x16x32_f16(ones8, u.v8, l[2 * h2 + q2], 0, 0, 0);
        }
    }
    // PV: read each V fragment once, feed all 4 qg
    __builtin_amdgcn_s_setprio(1);
#pragma unroll
    for (int dt = 0; dt < 4; dt++)
#pragma unroll
      for (int n2 = 0; n2 < 2; n2++) {
        half8 vv = *reinterpret_cast<const half8*>(&SM[voff[dt][n2] + BUFOFF]);
        o[0][dt] = __builtin_amdgcn_mfma_f32_16x16x32_f16(vv, pB[0][n2], o[0][dt], 0, 0, 0);
        o[1][dt] = __builtin_amdgcn_mfma_f32_16x16x32_f16(vv, pB[1][n2], o[1][dt], 0, 0, 0);
        o[2][dt] = __builtin_amdgcn_mfma_f32_16x16x32_f16(vv, pB[2][n2], o[2][dt], 0, 0, 0);
        o[3][dt] = __builtin_amdgcn_mfma_f32_16x16x32_f16(vv, pB[3][n2], o[3][dt], 0, 0, 0);
      }
    __builtin_amdgcn_s_setprio(0);
  };

  for (int ob2 = 0; ob2 < 16; ob2++) {
    __syncthreads();
    stage(16384, 4 * ob2 + 2);
    body(0);
    __syncthreads();
    if (ob2 < 15) stage(0, 4 * ob2 + 4);
    body(16384);
  }

  // combine even/odd partials: plain sums -> exact addition.
  // per wl: 16 o-vecs + 1 packed-l vec = 17 vecs x 64 lanes x 16 B; 2 wl = 34 KB.
  __syncthreads();
  float* cb = (float*)SM;
  if (par == 1) {
#pragma unroll
    for (int qg = 0; qg < 4; qg++)
#pragma unroll
      for (int dt = 0; dt < 4; dt++)
        *reinterpret_cast<f32x4*>(cb + ((wl * 17 + qg * 4 + dt) * 64 + L) * 4) = o[qg][dt];
    f32x4 lv = {l[0][0], l[1][0], l[2][0], l[3][0]};
    *reinterpret_cast<f32x4*>(cb + ((wl * 17 + 16) * 64 + L) * 4) = lv;
  }
  __syncthreads();
  if (par == 0) {
#pragma unroll
    for (int qg = 0; qg < 4; qg++)
#pragma unroll
      for (int dt = 0; dt < 4; dt++)
        o[qg][dt] += *reinterpret_cast<const f32x4*>(cb + ((wl * 17 + qg * 4 + dt) * 64 + L) * 4);
    f32x4 lv = *reinterpret_cast<const f32x4*>(cb + ((wl * 17 + 16) * 64 + L) * 4);
#pragma unroll
    for (int qg = 0; qg < 4; qg++) {
      float inv = 1.f / (l[qg][0] + lv[qg]);
      int q = qb * 128 + wl * 64 + qg * 16 + c;
#pragma unroll
      for (int dt = 0; dt < 4; dt++) {
        half4 hv;
#pragma unroll
        for (int r = 0; r < 4; r++) hv[r] = (_Float16)(o[qg][dt][r] * inv);
        *reinterpret_cast<half4*>(&O[(size_t)q * 1024 + h * 64 + dt * 16 + quad * 4]) = hv;
      }
    }
  }
}

extern "C" void kernel_launch(void* const* d_in, const int* in_sizes, int n_in,
                              void* d_out, int out_size, void* d_ws, size_t ws_size,
                              hipStream_t stream) {
  const float* x  = (const float*)d_in[0];
  const float* Wq = (const float*)d_in[1];
  const float* bq = (const float*)d_in[2];
  const float* Wk = (const float*)d_in[3];
  const float* bk = (const float*)d_in[4];
  const float* Wv = (const float*)d_in[5];
  const float* bv = (const float*)d_in[6];
  const float* Wo = (const float*)d_in[7];
  const float* bo = (const float*)d_in[8];

  char* ws = (char*)d_ws;
  const size_t MB = 1u << 20;
  unsigned short* xb  = (unsigned short*)(ws);            // 8 MB  x as f16
  unsigned short* Wqt = (unsigned short*)(ws + 8 * MB);   // 2 MB each, transposed f16
  unsigned short* Wkt = (unsigned short*)(ws + 10 * MB);
  unsigned short* Wvt = (unsigned short*)(ws + 12 * MB);
  unsigned short* Wot = (unsigned short*)(ws + 14 * MB);
  unsigned short* Qb  = (unsigned short*)(ws + 16 * MB);  // 8 MB [h][s][d]
  unsigned short* Kb  = (unsigned short*)(ws + 24 * MB);  // 8 MB [h][s][d]
  unsigned short* Vtg = (unsigned short*)(ws + 32 * MB);  // 8 MB [h][d][perm(s)]
  unsigned short* Ob  = (unsigned short*)(ws + 40 * MB);  // 8 MB [s][e]  (total 48 MB)

  // ATTRIBUTION: prep 3x and gemmO 3x (both idempotent).
  // dur_us - 212.6 = 2*(t_prep + t_gemmO).
  k_prep<<<5120, 256, 0, stream>>>(x, Wq, Wk, Wv, Wo, xb, Wqt, Wkt, Wvt, Wot);
  k_prep<<<5120, 256, 0, stream>>>(x, Wq, Wk, Wv, Wo, xb, Wqt, Wkt, Wvt, Wot);
  k_prep<<<5120, 256, 0, stream>>>(x, Wq, Wk, Wv, Wo, xb, Wqt, Wkt, Wvt, Wot);
  k_gemm<<<256, 512, 0, stream>>>(xb, Wqt, Wkt, Wvt, bq, bk, bv,
                                  (void*)Qb, (void*)Kb, (void*)Vtg);
  k_attn<<<dim3(32, 16), 256, 0, stream>>>(Qb, Kb, Vtg, Ob);
  k_gemmO<<<512, 256, 0, stream>>>(Ob, Wot, bo, (float*)d_out);
  k_gemmO<<<512, 256, 0, stream>>>(Ob, Wot, bo, (float*)d_out);
  k_gemmO<<<512, 256, 0, stream>>>(Ob, Wot, bo, (float*)d_out);
}

// Round 13
// 210.181 us; speedup vs baseline: 1.3059x; 1.2471x over previous
//
#include <hip/hip_runtime.h>

// MultiHeadedAttention: B=1, S=4096, E=1024, H=16, D=64, fp32 in/out.
// R20: HETEROGENEOUS BODY VARIANTS for attn MFMA/VALU overlap.
//   Budget (R18/R19 measured): attn 74.4 + gemm 31 + prep/gemmO 24.7 =
//   130us kernels; ~82us harness/dispatch fixed. Attn counter invariant
//   MfmaUtil44+VALU41+idle ~= 100% = zero pipe overlap. R15 failed because
//   reordering h2 halves keeps the pipe-TYPE sequence identical (MVMVM).
//   Fix: two variants with DIFFERENT type sequences — A: [QK0,exp0],
//   [QK1,exp1],PV (MVMVM); B: QK0,QK1,exp0,exp1,PV (MMVVM) — keyed per
//   block by (qb+(h>>3))&1 (flips for (i,i+1) and (i,i+256) co-residency
//   pairings). A-wave's exp overlaps B-wave's QK on the shared SIMD (m114).
//   Bit-identical math; B holds both st halves (+32 VGPR -> ~150).
// KNOWN: t_gemm=31us (832 TF, structure ceiling; 8-phase blocked by LDS
//   capacity at fused-3z tile); t_prep+t_gemmO=24.7us (near floors).
// NOTE (R8):  cross-body software pipelining of attn spills to scratch.
// NOTE (R10): in-wave VALU/MFMA interleave pinning regresses.
// NOTE (R16/R17): cross-kernel fusion dead (races / graph capture).

constexpr int Sq = 4096;
constexpr int Ee = 1024;
constexpr int Hh = 16;
constexpr int Dh = 64;

typedef _Float16 half8 __attribute__((ext_vector_type(8)));
typedef _Float16 half4 __attribute__((ext_vector_type(4)));
typedef _Float16 half2t __attribute__((ext_vector_type(2)));
typedef float f32x4 __attribute__((ext_vector_type(4)));

union U8 { half8 v8; half2t h2[4]; };

template <int N> struct IC { static constexpr int value = N; };

__device__ __forceinline__ unsigned short f2h(float f) {
  _Float16 h = (_Float16)f;
  return *reinterpret_cast<unsigned short*>(&h);
}

__device__ __forceinline__ half2t pk(float a, float b) {
  return __builtin_bit_cast(half2t, __builtin_amdgcn_cvt_pkrtz(a, b));
}

__device__ __forceinline__ void gload16(const void* g, void* l) {
  __builtin_amdgcn_global_load_lds(
      (const __attribute__((address_space(1))) void*)g,
      (__attribute__((address_space(3))) void*)l, 16, 0, 0);
}

// ---- fused prep: x fp32->f16 (blocks 0..4095) + 4 weight transposes ----
__global__ void k_prep(const float* __restrict__ x,
                       const float* __restrict__ Wq, const float* __restrict__ Wk,
                       const float* __restrict__ Wv, const float* __restrict__ Wo,
                       unsigned short* __restrict__ xb,
                       unsigned short* __restrict__ Wqt, unsigned short* __restrict__ Wkt,
                       unsigned short* __restrict__ Wvt, unsigned short* __restrict__ Wot) {
  int b = blockIdx.x, t = threadIdx.x;
  if (b < 4096) {
    int i = b * 256 + t;
    float4 v = reinterpret_cast<const float4*>(x)[i];
    ushort4 o;
    o.x = f2h(v.x); o.y = f2h(v.y); o.z = f2h(v.z); o.w = f2h(v.w);
    reinterpret_cast<ushort4*>(xb)[i] = o;
    return;
  }
  __shared__ unsigned short tile[64][65];
  int r = b - 4096;
  int wi = r >> 8, ti = r & 255;
  const float* W = (wi == 0) ? Wq : (wi == 1) ? Wk : (wi == 2) ? Wv : Wo;
  unsigned short* Wt = (wi == 0) ? Wqt : (wi == 1) ? Wkt : (wi == 2) ? Wvt : Wot;
  int kb = (ti & 15) * 64, nb = (ti >> 4) * 64;
  int r0 = t >> 4, c4 = (t & 15) * 4;
  for (int i = 0; i < 4; i++) {
    int row = r0 + i * 16;
    float4 v = *reinterpret_cast<const float4*>(W + (size_t)(kb + row) * Ee + nb + c4);
    tile[row][c4 + 0] = f2h(v.x); tile[row][c4 + 1] = f2h(v.y);
    tile[row][c4 + 2] = f2h(v.z); tile[row][c4 + 3] = f2h(v.w);
  }
  __syncthreads();
  for (int i = 0; i < 4; i++) {
    int nrow = r0 + i * 16;
    ushort4 o;
    o.x = tile[c4 + 0][nrow]; o.y = tile[c4 + 1][nrow];
    o.z = tile[c4 + 2][nrow]; o.w = tile[c4 + 3][nrow];
    *reinterpret_cast<ushort4*>(Wt + (size_t)(nb + nrow) * Ee + kb + c4) = o;
  }
}

// ---- z-fused QKV GEMM (R13): BM=128, BK=64, 512 thr, grid 256 ----
__global__ __launch_bounds__(512, 2) void k_gemm(
    const unsigned short* __restrict__ A,
    const unsigned short* __restrict__ W0, const unsigned short* __restrict__ W1,
    const unsigned short* __restrict__ W2,
    const float* __restrict__ b0, const float* __restrict__ b1, const float* __restrict__ b2,
    void* d0, void* d1, void* d2) {
  __shared__ __align__(16) unsigned short Al[2 * 8192];      // 32 KB
  __shared__ __align__(16) unsigned short Bl[2 * 3 * 8192];  // 96 KB
  int bid = blockIdx.x;
  int yp = bid & 7;   // n-panel -> XCD id
  int xm = bid >> 3;  // m-tile 0..31
  int m0 = xm * 128, n0 = yp * 128;

  int t = threadIdx.x;
  int w = t >> 6, L = t & 63, quad = L >> 4, c = L & 15;
  int wm = w >> 2, wn = w & 3;  // wave -> 64-row x 32-col subtile

  const unsigned short* Wz[3] = {W0, W1, W2};

  f32x4 zero = {0.f, 0.f, 0.f, 0.f};
  f32x4 acc[3][4][2];
#pragma unroll
  for (int z = 0; z < 3; z++)
#pragma unroll
    for (int a = 0; a < 4; a++)
#pragma unroll
      for (int b = 0; b < 2; b++) acc[z][a][b] = zero;

  auto stageAB = [&](int buf, int k0) {
#pragma unroll
    for (int i = 0; i < 2; i++) {
      int ch = i * 512 + t;
      int row = ch >> 3, kg = (ch & 7) ^ (row & 7);
      gload16(A + (size_t)(m0 + row) * 1024 + k0 + kg * 8, &Al[buf * 8192 + ch * 8]);
    }
#pragma unroll
    for (int z = 0; z < 3; z++)
#pragma unroll
      for (int i = 0; i < 2; i++) {
        int ch = i * 512 + t;
        int row = ch >> 3, kg = (ch & 7) ^ (row & 7);
        gload16(Wz[z] + (size_t)(n0 + row) * 1024 + k0 + kg * 8,
                &Bl[(buf * 3 + z) * 8192 + ch * 8]);
      }
  };

  auto compute = [&](int cur) {
    const unsigned short* Ab = &Al[cur * 8192];
#pragma unroll
    for (int ks = 0; ks < 2; ks++) {
      half8 af[4];
#pragma unroll
      for (int a = 0; a < 4; a++) {
        int row = wm * 64 + a * 16 + c;
        int kg = (quad + 4 * ks) ^ (row & 7);
        af[a] = *reinterpret_cast<const half8*>(&Ab[row * 64 + kg * 8]);
      }
#pragma unroll
      for (int z = 0; z < 3; z++) {
        const unsigned short* Bb = &Bl[(cur * 3 + z) * 8192];
        half8 bfr[2];
#pragma unroll
        for (int b = 0; b < 2; b++) {
          int row = wn * 32 + b * 16 + c;
          int kg = (quad + 4 * ks) ^ (row & 7);
          bfr[b] = *reinterpret_cast<const half8*>(&Bb[row * 64 + kg * 8]);
        }
#pragma unroll
        for (int a = 0; a < 4; a++)
#pragma unroll
          for (int b = 0; b < 2; b++) {
            if (z < 2)  // C^T: W-frag as A-operand
              acc[z][a][b] = __builtin_amdgcn_mfma_f32_16x16x32_f16(bfr[b], af[a], acc[z][a][b], 0, 0, 0);
            else        // C: A-frag as A-operand
              acc[z][a][b] = __builtin_amdgcn_mfma_f32_16x16x32_f16(af[a], bfr[b], acc[z][a][b], 0, 0, 0);
          }
      }
    }
  };

  stageAB(0, 0);
  stageAB(1, 64);
  for (int k0 = 0; k0 < 960; k0 += 64) {
    int cur = (k0 >> 6) & 1;
    asm volatile("s_waitcnt vmcnt(8)" ::: "memory");
    __builtin_amdgcn_s_barrier();
    __builtin_amdgcn_sched_barrier(0);
    compute(cur);
    __builtin_amdgcn_s_barrier();
    if (k0 < 896) stageAB(cur, k0 + 128);
  }
  asm volatile("s_waitcnt vmcnt(0)" ::: "memory");
  __builtin_amdgcn_s_barrier();
  __builtin_amdgcn_sched_barrier(0);
  compute(1);

  // ---- epilogues ----
  {
#pragma unroll
    for (int z = 0; z < 2; z++) {
      float sc = (z == 0) ? 0.18033688011112042f : 1.0f;
      const float* bias = (z == 0) ? b0 : b1;
      unsigned short* qk = (unsigned short*)((z == 0) ? d0 : d1);
#pragma unroll
      for (int b = 0; b < 2; b++) {
        int nb4 = n0 + wn * 32 + b * 16 + quad * 4;
        int hh = nb4 >> 6, d = nb4 & 63;
        f32x4 b4 = *reinterpret_cast<const f32x4*>(bias + nb4);
#pragma unroll
        for (int a = 0; a < 4; a++) {
          int s = m0 + wm * 64 + a * 16 + c;
          half4 hv;
#pragma unroll
          for (int r = 0; r < 4; r++) hv[r] = (_Float16)((acc[z][a][b][r] + b4[r]) * sc);
          *reinterpret_cast<half4*>(&qk[(size_t)hh * Sq * Dh + (size_t)s * Dh + d]) = hv;
        }
      }
    }
  }
  {
    unsigned short* Vt = (unsigned short*)d2;
#pragma unroll
    for (int b = 0; b < 2; b++) {
      int n = n0 + wn * 32 + b * 16 + c;
      int hh = n >> 6, d = n & 63;
      float bvf = b2[n];
#pragma unroll
      for (int a = 0; a < 4; a++) {
        int pos = m0 + wm * 64 + (a >> 1) * 32 + quad * 8 + (a & 1) * 4;
        half4 hv;
#pragma unroll
        for (int r = 0; r < 4; r++) hv[r] = (_Float16)(acc[2][a][b][r] + bvf);
        *reinterpret_cast<half4*>(&Vt[(size_t)hh * Dh * Sq + (size_t)d * Sq + pos]) = hv;
      }
    }
  }
}

// ---- Output GEMM: 64x128 tiles, 1-D grid 512 (bid&7 = n-panel/XCD) ----
__global__ __launch_bounds__(256) void k_gemmO(
    const unsigned short* __restrict__ A, const unsigned short* __restrict__ Wt,
    const float* __restrict__ bias, float* __restrict__ out) {
  __shared__ __align__(16) unsigned short Al[2 * 64 * 64];   // 16 KB
  __shared__ __align__(16) unsigned short Bl[2 * 128 * 64];  // 32 KB
  int bid = blockIdx.x;
  int yp = bid & 7;
  int xm = bid >> 3;
  int t = threadIdx.x;
  int w = t >> 6, L = t & 63, quad = L >> 4, c = L & 15;
  int m0 = xm * 64, n0 = yp * 128;
  int wm = w & 1, wn = w >> 1;

  f32x4 zero = {0.f, 0.f, 0.f, 0.f};
  f32x4 acc[4][2];
#pragma unroll
  for (int j = 0; j < 4; j++)
#pragma unroll
    for (int i = 0; i < 2; i++) acc[j][i] = zero;

  auto stageAB = [&](int buf, int k0) {
#pragma unroll
    for (int i = 0; i < 2; i++) {
      int ch = i * 256 + t;
      int row = ch >> 3, kg = (ch & 7) ^ (row & 7);
      gload16(A + (size_t)(m0 + row) * 1024 + k0 + kg * 8, &Al[buf * 4096 + ch * 8]);
    }
#pragma unroll
    for (int i = 0; i < 4; i++) {
      int ch = i * 256 + t;
      int row = ch >> 3, kg = (ch & 7) ^ (row & 7);
      gload16(Wt + (size_t)(n0 + row) * 1024 + k0 + kg * 8, &Bl[buf * 8192 + ch * 8]);
    }
  };
  auto compute = [&](int cur) {
    const unsigned short* Ab = &Al[cur * 4096];
    const unsigned short* Bb = &Bl[cur * 8192];
#pragma unroll
    for (int ks = 0; ks < 2; ks++) {
      half8 af[2], bfr[4];
#pragma unroll
      for (int i = 0; i < 2; i++) {
        int row = wm * 32 + i * 16 + c;
        int kg = (quad + 4 * ks) ^ (row & 7);
        af[i] = *reinterpret_cast<const half8*>(&Ab[row * 64 + kg * 8]);
      }
#pragma unroll
      for (int j = 0; j < 4; j++) {
        int row = wn * 64 + j * 16 + c;
        int kg = (quad + 4 * ks) ^ (row & 7);
        bfr[j] = *reinterpret_cast<const half8*>(&Bb[row * 64 + kg * 8]);
      }
#pragma unroll
      for (int j = 0; j < 4; j++)
#pragma unroll
        for (int i = 0; i < 2; i++)
          acc[j][i] = __builtin_amdgcn_mfma_f32_16x16x32_f16(bfr[j], af[i], acc[j][i], 0, 0, 0);
    }
  };
  stageAB(0, 0);
  stageAB(1, 64);
  for (int k0 = 0; k0 < 960; k0 += 64) {
    int cur = (k0 >> 6) & 1;
    asm volatile("s_waitcnt vmcnt(6)" ::: "memory");
    __builtin_amdgcn_s_barrier();
    __builtin_amdgcn_sched_barrier(0);
    compute(cur);
    __builtin_amdgcn_s_barrier();
    if (k0 < 896) stageAB(cur, k0 + 128);
  }
  asm volatile("s_waitcnt vmcnt(0)" ::: "memory");
  __builtin_amdgcn_s_barrier();
  __builtin_amdgcn_sched_barrier(0);
  compute(1);

#pragma unroll
  for (int j = 0; j < 4; j++) {
    int nb4 = n0 + wn * 64 + j * 16 + quad * 4;
    f32x4 b4 = *reinterpret_cast<const f32x4*>(bias + nb4);
#pragma unroll
    for (int i = 0; i < 2; i++) {
      int s = m0 + wm * 32 + i * 16 + c;
      f32x4 v = acc[j][i] + b4;
      *reinterpret_cast<f32x4*>(out + (size_t)s * 1024 + nb4) = v;
    }
  }
}

// ---- flash attention, S^T/O^T form, heterogeneous body variants ----
// Q,K [h][s][64] f16 (Q pre-scaled), Vt [h][64][perm(s)] f16 -> O [s][1024] f16
// 256 threads = 4 waves; par=w>>1 key parity, wl=w&1 owns 64 q-rows (qg=4).
// Grid (32,16) = 512 blocks = 2/CU. Variant keyed by block identity:
//   A (MVMVM): [QK0,exp0],[QK1,exp1],PV   B (MMVVM): QK0,QK1,exp0,exp1,PV
// Co-resident blocks get opposite variants -> SIMD-mates' M/V phases overlap.
__global__ __launch_bounds__(256, 2) void k_attn(
    const unsigned short* __restrict__ Q, const unsigned short* __restrict__ K,
    const unsigned short* __restrict__ Vt, unsigned short* __restrict__ O) {
  __shared__ __align__(16) unsigned short SM[32768];  // 64 KB
  int t = threadIdx.x;
  int w = t >> 6, L = t & 63, quad = L >> 4, c = L & 15;
  int wl = w & 1, par = w >> 1;
  int h = blockIdx.y, qb = blockIdx.x;
  // variant key: flips for (i,i+1) [qb parity] and (i,i+256) [h>>3] pairings
  bool keyB = ((qb + (h >> 3)) & 1) != 0;
  const unsigned short* Qh = Q + (size_t)h * Sq * Dh;
  const unsigned short* Kh = K + (size_t)h * Sq * Dh;
  const unsigned short* Vth = Vt + (size_t)h * Dh * Sq;

  half8 qf[4][2];
#pragma unroll
  for (int qg = 0; qg < 4; qg++) {
    int qrow = qb * 128 + wl * 64 + qg * 16 + c;
#pragma unroll
    for (int ks = 0; ks < 2; ks++)
      qf[qg][ks] = *reinterpret_cast<const half8*>(Qh + (size_t)qrow * Dh + ks * 32 + quad * 8);
  }

  f32x4 zero = {0.f, 0.f, 0.f, 0.f};
  f32x4 o[4][4];
  f32x4 l[4];
#pragma unroll
  for (int qg = 0; qg < 4; qg++) {
    l[qg] = zero;
#pragma unroll
    for (int dt = 0; dt < 4; dt++) o[qg][dt] = zero;
  }
  half8 ones8;
#pragma unroll
  for (int j = 0; j < 8; j++) ones8[j] = (_Float16)1.0f;

  int koff[2][4], voff[4][2];
#pragma unroll
  for (int ks = 0; ks < 2; ks++)
#pragma unroll
    for (int nt = 0; nt < 4; nt++) {
      int row = nt * 16 + c;
      koff[ks][nt] = par * 4096 + row * 64 + (((ks * 4 + quad) ^ (row & 7)) * 8);
    }
#pragma unroll
  for (int dt = 0; dt < 4; dt++)
#pragma unroll
    for (int n2 = 0; n2 < 2; n2++) {
      int row = dt * 16 + c;
      voff[dt][n2] = (2 + par) * 4096 + row * 64 + (((n2 * 4 + quad) ^ (row & 7)) * 8);
    }

  const unsigned short* KgB[2];
  const unsigned short* VgB[2];
#pragma unroll
  for (int i = 0; i < 2; i++) {
    int ch = i * 256 + t;
    int row = ch >> 3, kg = (ch & 7) ^ (row & 7);
    KgB[i] = Kh + row * Dh + kg * 8;           // + tb*4096
    VgB[i] = Vth + (size_t)row * Sq + kg * 8;  // + tb*64
  }

  auto stage = [&](int bufo, int tb) {
#pragma unroll
    for (int p2 = 0; p2 < 2; p2++) {
#pragma unroll
      for (int i = 0; i < 2; i++)
        gload16(KgB[i] + (size_t)(tb + p2) * 4096, &SM[bufo + p2 * 4096 + (i * 256 + t) * 8]);
#pragma unroll
      for (int i = 0; i < 2; i++)
        gload16(VgB[i] + (size_t)(tb + p2) * 64, &SM[bufo + (2 + p2) * 4096 + (i * 256 + t) * 8]);
    }
  };

  stage(0, 0);

  // pack-unit: st pair -> 16 exp2 -> packed half8 -> pB + rowsum MFMA
  auto packu = [&](f32x4 (&stq)[4], int n2, half8& pBq, f32x4& lq) {
    U8 u;
    u.h2[0] = pk(__builtin_amdgcn_exp2f(stq[2 * n2][0]), __builtin_amdgcn_exp2f(stq[2 * n2][1]));
    u.h2[1] = pk(__builtin_amdgcn_exp2f(stq[2 * n2][2]), __builtin_amdgcn_exp2f(stq[2 * n2][3]));
    u.h2[2] = pk(__builtin_amdgcn_exp2f(stq[2 * n2 + 1][0]), __builtin_amdgcn_exp2f(stq[2 * n2 + 1][1]));
    u.h2[3] = pk(__builtin_amdgcn_exp2f(stq[2 * n2 + 1][2]), __builtin_amdgcn_exp2f(stq[2 * n2 + 1][3]));
    pBq = u.v8;
    lq = __builtin_amdgcn_mfma_f32_16x16x32_f16(ones8, u.v8, lq, 0, 0, 0);
  };

  auto run = [&](auto BC) {
    constexpr int BATCH = BC.value;
    auto body = [&](int BUFOFF) {
      half8 pB[4][2];
      if constexpr (BATCH) {
        // variant B: QK0, QK1 (pure MFMA), then exp0, exp1 (pure VALU)
        f32x4 st[2][2][4];  // [h2][q2][nt]
        __builtin_amdgcn_s_setprio(1);
#pragma unroll
        for (int h2 = 0; h2 < 2; h2++) {
#pragma unroll
          for (int nt = 0; nt < 4; nt++) {
            half8 kfv = *reinterpret_cast<const half8*>(&SM[koff[0][nt] + BUFOFF]);
            st[h2][0][nt] = __builtin_amdgcn_mfma_f32_16x16x32_f16(kfv, qf[2 * h2 + 0][0], zero, 0, 0, 0);
            st[h2][1][nt] = __builtin_amdgcn_mfma_f32_16x16x32_f16(kfv, qf[2 * h2 + 1][0], zero, 0, 0, 0);
          }
#pragma unroll
          for (int nt = 0; nt < 4; nt++) {
            half8 kfv = *reinterpret_cast<const half8*>(&SM[koff[1][nt] + BUFOFF]);
            st[h2][0][nt] = __builtin_amdgcn_mfma_f32_16x16x32_f16(kfv, qf[2 * h2 + 0][1], st[h2][0][nt], 0, 0, 0);
            st[h2][1][nt] = __builtin_amdgcn_mfma_f32_16x16x32_f16(kfv, qf[2 * h2 + 1][1], st[h2][1][nt], 0, 0, 0);
          }
        }
        __builtin_amdgcn_s_setprio(0);
#pragma unroll
        for (int h2 = 0; h2 < 2; h2++)
#pragma unroll
          for (int q2 = 0; q2 < 2; q2++)
#pragma unroll
            for (int n2 = 0; n2 < 2; n2++)
              packu(st[h2][q2], n2, pB[2 * h2 + q2][n2], l[2 * h2 + q2]);
      } else {
        // variant A (R9 form): [QK0, exp0], [QK1, exp1]
#pragma unroll
        for (int h2 = 0; h2 < 2; h2++) {
          f32x4 st[2][4];
          __builtin_amdgcn_s_setprio(1);
#pragma unroll
          for (int nt = 0; nt < 4; nt++) {
            half8 kfv = *reinterpret_cast<const half8*>(&SM[koff[0][nt] + BUFOFF]);
            st[0][nt] = __builtin_amdgcn_mfma_f32_16x16x32_f16(kfv, qf[2 * h2 + 0][0], zero, 0, 0, 0);
            st[1][nt] = __builtin_amdgcn_mfma_f32_16x16x32_f16(kfv, qf[2 * h2 + 1][0], zero, 0, 0, 0);
          }
#pragma unroll
          for (int nt = 0; nt < 4; nt++) {
            half8 kfv = *reinterpret_cast<const half8*>(&SM[koff[1][nt] + BUFOFF]);
            st[0][nt] = __builtin_amdgcn_mfma_f32_16x16x32_f16(kfv, qf[2 * h2 + 0][1], st[0][nt], 0, 0, 0);
            st[1][nt] = __builtin_amdgcn_mfma_f32_16x16x32_f16(kfv, qf[2 * h2 + 1][1], st[1][nt], 0, 0, 0);
          }
          __builtin_amdgcn_s_setprio(0);
#pragma unroll
          for (int q2 = 0; q2 < 2; q2++)
#pragma unroll
            for (int n2 = 0; n2 < 2; n2++)
              packu(st[q2], n2, pB[2 * h2 + q2][n2], l[2 * h2 + q2]);
        }
      }
      // PV: read each V fragment once, feed all 4 qg
      __builtin_amdgcn_s_setprio(1);
#pragma unroll
      for (int dt = 0; dt < 4; dt++)
#pragma unroll
        for (int n2 = 0; n2 < 2; n2++) {
          half8 vv = *reinterpret_cast<const half8*>(&SM[voff[dt][n2] + BUFOFF]);
          o[0][dt] = __builtin_amdgcn_mfma_f32_16x16x32_f16(vv, pB[0][n2], o[0][dt], 0, 0, 0);
          o[1][dt] = __builtin_amdgcn_mfma_f32_16x16x32_f16(vv, pB[1][n2], o[1][dt], 0, 0, 0);
          o[2][dt] = __builtin_amdgcn_mfma_f32_16x16x32_f16(vv, pB[2][n2], o[2][dt], 0, 0, 0);
          o[3][dt] = __builtin_amdgcn_mfma_f32_16x16x32_f16(vv, pB[3][n2], o[3][dt], 0, 0, 0);
        }
      __builtin_amdgcn_s_setprio(0);
    };

    for (int ob2 = 0; ob2 < 16; ob2++) {
      __syncthreads();
      stage(16384, 4 * ob2 + 2);
      body(0);
      __syncthreads();
      if (ob2 < 15) stage(0, 4 * ob2 + 4);
      body(16384);
    }
  };
  if (keyB) run(IC<1>{});
  else      run(IC<0>{});

  // combine even/odd partials: plain sums -> exact addition.
  __syncthreads();
  float* cb = (float*)SM;
  if (par == 1) {
#pragma unroll
    for (int qg = 0; qg < 4; qg++)
#pragma unroll
      for (int dt = 0; dt < 4; dt++)
        *reinterpret_cast<f32x4*>(cb + ((wl * 17 + qg * 4 + dt) * 64 + L) * 4) = o[qg][dt];
    f32x4 lv = {l[0][0], l[1][0], l[2][0], l[3][0]};
    *reinterpret_cast<f32x4*>(cb + ((wl * 17 + 16) * 64 + L) * 4) = lv;
  }
  __syncthreads();
  if (par == 0) {
#pragma unroll
    for (int qg = 0; qg < 4; qg++)
#pragma unroll
      for (int dt = 0; dt < 4; dt++)
        o[qg][dt] += *reinterpret_cast<const f32x4*>(cb + ((wl * 17 + qg * 4 + dt) * 64 + L) * 4);
    f32x4 lv = *reinterpret_cast<const f32x4*>(cb + ((wl * 17 + 16) * 64 + L) * 4);
#pragma unroll
    for (int qg = 0; qg < 4; qg++) {
      float inv = 1.f / (l[qg][0] + lv[qg]);
      int q = qb * 128 + wl * 64 + qg * 16 + c;
#pragma unroll
      for (int dt = 0; dt < 4; dt++) {
        half4 hv;
#pragma unroll
        for (int r = 0; r < 4; r++) hv[r] = (_Float16)(o[qg][dt][r] * inv);
        *reinterpret_cast<half4*>(&O[(size_t)q * 1024 + h * 64 + dt * 16 + quad * 4]) = hv;
      }
    }
  }
}

extern "C" void kernel_launch(void* const* d_in, const int* in_sizes, int n_in,
                              void* d_out, int out_size, void* d_ws, size_t ws_size,
                              hipStream_t stream) {
  const float* x  = (const float*)d_in[0];
  const float* Wq = (const float*)d_in[1];
  const float* bq = (const float*)d_in[2];
  const float* Wk = (const float*)d_in[3];
  const float* bk = (const float*)d_in[4];
  const float* Wv = (const float*)d_in[5];
  const float* bv = (const float*)d_in[6];
  const float* Wo = (const float*)d_in[7];
  const float* bo = (const float*)d_in[8];

  char* ws = (char*)d_ws;
  const size_t MB = 1u << 20;
  unsigned short* xb  = (unsigned short*)(ws);            // 8 MB  x as f16
  unsigned short* Wqt = (unsigned short*)(ws + 8 * MB);   // 2 MB each, transposed f16
  unsigned short* Wkt = (unsigned short*)(ws + 10 * MB);
  unsigned short* Wvt = (unsigned short*)(ws + 12 * MB);
  unsigned short* Wot = (unsigned short*)(ws + 14 * MB);
  unsigned short* Qb  = (unsigned short*)(ws + 16 * MB);  // 8 MB [h][s][d]
  unsigned short* Kb  = (unsigned short*)(ws + 24 * MB);  // 8 MB [h][s][d]
  unsigned short* Vtg = (unsigned short*)(ws + 32 * MB);  // 8 MB [h][d][perm(s)]
  unsigned short* Ob  = (unsigned short*)(ws + 40 * MB);  // 8 MB [s][e]  (total 48 MB)

  k_prep<<<5120, 256, 0, stream>>>(x, Wq, Wk, Wv, Wo, xb, Wqt, Wkt, Wvt, Wot);
  k_gemm<<<256, 512, 0, stream>>>(xb, Wqt, Wkt, Wvt, bq, bk, bv,
                                  (void*)Qb, (void*)Kb, (void*)Vtg);
  k_attn<<<dim3(32, 16), 256, 0, stream>>>(Qb, Kb, Vtg, Ob);
  k_gemmO<<<512, 256, 0, stream>>>(Ob, Wot, bo, (float*)d_out);
}